// Round 4
// baseline (427.347 us; speedup 1.0000x reference)
//
#include <hip/hip_runtime.h>
#include <hip/hip_bf16.h>

typedef __attribute__((ext_vector_type(8)))  short          bf16x8;
typedef __attribute__((ext_vector_type(8)))  unsigned short us8;
typedef __attribute__((ext_vector_type(4)))  unsigned short us4;
typedef __attribute__((ext_vector_type(16))) float          f32x16;

static __device__ __forceinline__ unsigned short f2bf(float f) {
    union { float f; unsigned int u; } v; v.f = f;
    unsigned int u = v.u;
    unsigned int r = u + 0x7fffu + ((u >> 16) & 1u);
    return (unsigned short)(r >> 16);
}

static __device__ __forceinline__ bf16x8 pack8(float4 a, float4 b) {
    bf16x8 r;
    r[0] = (short)f2bf(a.x); r[1] = (short)f2bf(a.y);
    r[2] = (short)f2bf(a.z); r[3] = (short)f2bf(a.w);
    r[4] = (short)f2bf(b.x); r[5] = (short)f2bf(b.y);
    r[6] = (short)f2bf(b.z); r[7] = (short)f2bf(b.w);
    return r;
}

// block 0: W1 f32 -> bf16 (20480 elems). blocks 1..: x f32 -> bf16 (if do_x)
__global__ __launch_bounds__(256) void prep_kernel(
    const float* __restrict__ W1, const float* __restrict__ x,
    unsigned short* __restrict__ w1b, unsigned short* __restrict__ xb,
    int nx, int do_x)
{
    if (blockIdx.x == 0) {
        for (int i = threadIdx.x; i < 128 * 160; i += 256)
            w1b[i] = f2bf(W1[i]);
    } else if (do_x) {
        int n4 = nx >> 2;
        int idx = (blockIdx.x - 1) * 256 + threadIdx.x;
        int stride = (gridDim.x - 1) * 256;
        for (int i = idx; i < n4; i += stride) {
            float4 f = ((const float4*)x)[i];
            us4 o = { f2bf(f.x), f2bf(f.y), f2bf(f.z), f2bf(f.w) };
            ((us4*)xb)[i] = o;
        }
    }
}

#define MFMA4(AF, KS)                                                              \
    {                                                                              \
        const int kb_ = (KS) * 16 + kg * 8;                                        \
        acc[0] = __builtin_amdgcn_mfma_f32_32x32x16_bf16(                          \
            (AF), *(const bf16x8*)&W1s[0 * 32 + m][kb_], acc[0], 0, 0, 0);         \
        acc[1] = __builtin_amdgcn_mfma_f32_32x32x16_bf16(                          \
            (AF), *(const bf16x8*)&W1s[1 * 32 + m][kb_], acc[1], 0, 0, 0);         \
        acc[2] = __builtin_amdgcn_mfma_f32_32x32x16_bf16(                          \
            (AF), *(const bf16x8*)&W1s[2 * 32 + m][kb_], acc[2], 0, 0, 0);         \
        acc[3] = __builtin_amdgcn_mfma_f32_32x32x16_bf16(                          \
            (AF), *(const bf16x8*)&W1s[3 * 32 + m][kb_], acc[3], 0, 0, 0);         \
    }

// Persistent, software-pipelined: 768 blocks x ~10 tiles of 128 edges.
// W1 staged to LDS once per block; no per-tile barriers; next tile's
// gathers issued under current tile's MFMAs (WAR overwrite, single buffer).
__global__ __launch_bounds__(256, 3) void edge_mlp_pers(
    const unsigned short* __restrict__ xb,
    const int* __restrict__ ei, const float* __restrict__ ef,
    const unsigned short* __restrict__ w1b,
    const float* __restrict__ b1, const float* __restrict__ w2,
    const float* __restrict__ b2, float* __restrict__ out, int E)
{
    __shared__ unsigned short W1s[128][168];  // stride 336B: 16B-aligned, 4-way banks
    __shared__ float b1s[128];
    __shared__ float w2s[128];

    const int tid = threadIdx.x;
    {
        int j = tid >> 1, h = tid & 1;
        const unsigned short* src = w1b + j * 160 + h * 80;
        unsigned short* dst = &W1s[j][h * 80];
        #pragma unroll
        for (int i = 0; i < 10; i++)
            *(us8*)(dst + i * 8) = *(const us8*)(src + i * 8);
    }
    if (tid < 128) { b1s[tid] = b1[tid]; w2s[tid] = w2[tid]; }
    __syncthreads();

    const int lane = tid & 63;
    const int wv   = tid >> 6;
    const int m    = lane & 31;   // A row / B col / C col
    const int kg   = lane >> 5;   // k half: k = ks*16 + kg*8 + j
    const float b2v = b2[0];
    const int laneoff = wv * 32 + m;

    float b1v[4], w2v[4];
    #pragma unroll
    for (int nt = 0; nt < 4; nt++) {
        b1v[nt] = b1s[nt * 32 + m];
        w2v[nt] = w2s[nt * 32 + m];
    }

    const int ntiles = (E + 127) >> 7;
    const int NT = gridDim.x;
    int t = blockIdx.x;
    if (t >= ntiles) return;

    auto eclamp = [&](int tt) -> int {
        if (tt >= ntiles) tt = ntiles - 1;
        long e = (long)tt * 128 + laneoff;
        return (int)(e < (long)E ? e : (long)(E - 1));
    };

    const unsigned short* xk = xb + kg * 8;

    // ---- prologue: indices + gathers for tile t; indices for tile t+NT ----
    int eA = eclamp(t);
    int oA = ei[eA], dA = ei[(size_t)E + eA];
    int eB = eclamp(t + NT);
    int oB = ei[eB], dB = ei[(size_t)E + eB];

    bf16x8 xo[4], xd[4];
    float4 efr[4];
    {
        const bf16x8* po = (const bf16x8*)(xk + (size_t)oA * 64);
        const bf16x8* pd = (const bf16x8*)(xk + (size_t)dA * 64);
        #pragma unroll
        for (int ks = 0; ks < 4; ks++) { xo[ks] = po[ks * 2]; xd[ks] = pd[ks * 2]; }
        const float4* pe = (const float4*)(ef + (size_t)eA * 32 + kg * 8);
        efr[0] = pe[0]; efr[1] = pe[1]; efr[2] = pe[4]; efr[3] = pe[5];
    }

    while (true) {
        // pack current tile's ef (implicit waits on efr)
        bf16x8 af8 = pack8(efr[0], efr[1]);
        bf16x8 af9 = pack8(efr[2], efr[3]);

        // prefetch indices for tile t+2*NT
        int eC = eclamp(t + 2 * NT);
        int oC = ei[eC], dC = ei[(size_t)E + eC];

        f32x16 acc[4];
        #pragma unroll
        for (int i = 0; i < 4; i++)
            #pragma unroll
            for (int r = 0; r < 16; r++) acc[i][r] = 0.0f;

        const bf16x8* po = (const bf16x8*)(xk + (size_t)oB * 64);
        const bf16x8* pd = (const bf16x8*)(xk + (size_t)dB * 64);
        const float4* pe = (const float4*)(ef + (size_t)eB * 32 + kg * 8);

        // ---- MFMA + interleaved next-tile gather issue ----
        #pragma unroll
        for (int ks = 0; ks < 4; ks++) {
            MFMA4(xo[ks], ks);
            xo[ks] = po[ks * 2];          // overwrite after last use (tile t+NT)
        }
        #pragma unroll
        for (int ks = 0; ks < 4; ks++) {
            MFMA4(xd[ks], ks + 4);
            xd[ks] = pd[ks * 2];
        }
        MFMA4(af8, 8);
        efr[0] = pe[0]; efr[1] = pe[1];
        MFMA4(af9, 9);
        efr[2] = pe[4]; efr[3] = pe[5];

        // ---- epilogue: bias + leaky + W2 dot + butterfly reduce + store ----
        float s[16];
        #pragma unroll
        for (int r = 0; r < 16; r++) {
            float a = 0.0f;
            #pragma unroll
            for (int nt = 0; nt < 4; nt++) {
                float h = acc[nt][r] + b1v[nt];
                h = fmaxf(h, 0.01f * h);
                a = fmaf(h, w2v[nt], a);
            }
            s[r] = a;
        }
        #pragma unroll
        for (int k = 0; k < 4; k++) {
            const int msk = 1 << k;
            const int bit = (m >> k) & 1;
            #pragma unroll
            for (int j = 0; j < (8 >> k); j++) {
                float a0 = s[2 * j], a1 = s[2 * j + 1];
                float keep = bit ? a1 : a0;
                float send = bit ? a0 : a1;
                s[j] = keep + __shfl_xor(send, msk, 64);
            }
        }
        float tot = s[0] + __shfl_xor(s[0], 16, 64);

        if ((m & 16) == 0) {
            int row = (m & 3) + 4 * kg + 8 * ((m >> 2) & 3);
            long oidx = (long)t * 128 + wv * 32 + row;
            if (oidx < (long)E) {
                float v = tot + b2v;
                out[oidx] = fmaxf(v, 0.01f * v);
            }
        }

        t += NT;
        if (t >= ntiles) break;
        oB = oC; dB = dC; eB = eC;
    }
}

// Fallback (ws too small for xb): original non-persistent kernel, f32 gather.
__global__ __launch_bounds__(256) void edge_mlp_fb(
    const float* __restrict__ x,
    const int* __restrict__ ei, const float* __restrict__ ef,
    const unsigned short* __restrict__ w1b,
    const float* __restrict__ b1, const float* __restrict__ w2,
    const float* __restrict__ b2, float* __restrict__ out, int E)
{
    __shared__ unsigned short W1s[128][168];
    __shared__ float b1s[128];
    __shared__ float w2s[128];

    const int t = threadIdx.x;
    {
        int j = t >> 1, h = t & 1;
        const unsigned short* src = w1b + j * 160 + h * 80;
        unsigned short* dst = &W1s[j][h * 80];
        #pragma unroll
        for (int i = 0; i < 10; i++)
            *(us8*)(dst + i * 8) = *(const us8*)(src + i * 8);
    }
    if (t < 128) { b1s[t] = b1[t]; w2s[t] = w2[t]; }
    __syncthreads();

    const int lane = t & 63;
    const int wv   = t >> 6;
    const int m    = lane & 31;
    const int kg   = lane >> 5;
    const float b2v = b2[0];

    long e = (long)blockIdx.x * 128 + wv * 32 + m;
    int eidx = (int)((e < (long)E) ? e : (long)(E - 1));
    int o = ei[eidx];
    int d = ei[(size_t)E + eidx];

    bf16x8 afrag[10];
    {
        const float4* xo = (const float4*)(x + (size_t)o * 64 + kg * 8);
        const float4* xd = (const float4*)(x + (size_t)d * 64 + kg * 8);
        #pragma unroll
        for (int ks = 0; ks < 4; ks++) afrag[ks]     = pack8(xo[ks * 4], xo[ks * 4 + 1]);
        #pragma unroll
        for (int ks = 0; ks < 4; ks++) afrag[4 + ks] = pack8(xd[ks * 4], xd[ks * 4 + 1]);
        const float4* pef = (const float4*)(ef + (size_t)eidx * 32 + kg * 8);
        #pragma unroll
        for (int ks = 0; ks < 2; ks++)
            afrag[8 + ks] = pack8(pef[ks * 4], pef[ks * 4 + 1]);
    }

    f32x16 acc[4];
    #pragma unroll
    for (int i = 0; i < 4; i++)
        #pragma unroll
        for (int r = 0; r < 16; r++) acc[i][r] = 0.0f;

    #pragma unroll
    for (int ks = 0; ks < 10; ks++) {
        MFMA4(afrag[ks], ks);
    }

    float b1v[4], w2v[4];
    #pragma unroll
    for (int nt = 0; nt < 4; nt++) {
        b1v[nt] = b1s[nt * 32 + m];
        w2v[nt] = w2s[nt * 32 + m];
    }
    float s[16];
    #pragma unroll
    for (int r = 0; r < 16; r++) {
        float a = 0.0f;
        #pragma unroll
        for (int nt = 0; nt < 4; nt++) {
            float h = acc[nt][r] + b1v[nt];
            h = fmaxf(h, 0.01f * h);
            a = fmaf(h, w2v[nt], a);
        }
        s[r] = a;
    }
    #pragma unroll
    for (int k = 0; k < 4; k++) {
        const int msk = 1 << k;
        const int bit = (m >> k) & 1;
        #pragma unroll
        for (int j = 0; j < (8 >> k); j++) {
            float a0 = s[2 * j], a1 = s[2 * j + 1];
            float keep = bit ? a1 : a0;
            float send = bit ? a0 : a1;
            s[j] = keep + __shfl_xor(send, msk, 64);
        }
    }
    float tot = s[0] + __shfl_xor(s[0], 16, 64);

    if ((m & 16) == 0) {
        int row = (m & 3) + 4 * kg + 8 * ((m >> 2) & 3);
        long oidx = (long)blockIdx.x * 128 + wv * 32 + row;
        if (oidx < (long)E) {
            float v = tot + b2v;
            out[oidx] = fmaxf(v, 0.01f * v);
        }
    }
}

extern "C" void kernel_launch(void* const* d_in, const int* in_sizes, int n_in,
                              void* d_out, int out_size, void* d_ws, size_t ws_size,
                              hipStream_t stream)
{
    const float* x  = (const float*)d_in[0];
    const int*   ei = (const int*)d_in[1];
    const float* ef = (const float*)d_in[2];
    const float* W1 = (const float*)d_in[3];
    const float* b1 = (const float*)d_in[4];
    const float* w2 = (const float*)d_in[5];
    const float* b2 = (const float*)d_in[6];
    float* out = (float*)d_out;

    const int E  = in_sizes[1] / 2;
    const int nx = in_sizes[0];

    unsigned short* w1b = (unsigned short*)d_ws;
    unsigned short* xb  = (unsigned short*)((char*)d_ws + 65536);
    const bool use_xb = ws_size >= (size_t)65536 + (size_t)nx * 2;

    prep_kernel<<<use_xb ? 2048 : 1, 256, 0, stream>>>(W1, x, w1b, xb, nx, use_xb ? 1 : 0);
    if (use_xb) {
        edge_mlp_pers<<<768, 256, 0, stream>>>(xb, ei, ef, w1b, b1, w2, b2, out, E);
    } else {
        const int nblk = (E + 127) / 128;
        edge_mlp_fb<<<nblk, 256, 0, stream>>>(x, ei, ef, w1b, b1, w2, b2, out, E);
    }
}

// Round 6
// 264.486 us; speedup vs baseline: 1.6158x; 1.6158x over previous
//
#include <hip/hip_runtime.h>
#include <hip/hip_bf16.h>

typedef __attribute__((ext_vector_type(8)))  short          bf16x8;
typedef __attribute__((ext_vector_type(8)))  unsigned short us8;
typedef __attribute__((ext_vector_type(4)))  unsigned short us4;
typedef __attribute__((ext_vector_type(16))) float          f32x16;

static __device__ __forceinline__ unsigned short f2bf(float f) {
    union { float f; unsigned int u; } v; v.f = f;
    unsigned int u = v.u;
    unsigned int r = u + 0x7fffu + ((u >> 16) & 1u);
    return (unsigned short)(r >> 16);
}

static __device__ __forceinline__ bf16x8 pack8(float4 a, float4 b) {
    bf16x8 r;
    r[0] = (short)f2bf(a.x); r[1] = (short)f2bf(a.y);
    r[2] = (short)f2bf(a.z); r[3] = (short)f2bf(a.w);
    r[4] = (short)f2bf(b.x); r[5] = (short)f2bf(b.y);
    r[6] = (short)f2bf(b.z); r[7] = (short)f2bf(b.w);
    return r;
}

// block 0: W1 f32 -> bf16 (20480 elems). blocks 1..: x f32 -> bf16 (if do_x)
__global__ __launch_bounds__(256) void prep_kernel(
    const float* __restrict__ W1, const float* __restrict__ x,
    unsigned short* __restrict__ w1b, unsigned short* __restrict__ xb,
    int nx, int do_x)
{
    if (blockIdx.x == 0) {
        for (int i = threadIdx.x; i < 128 * 160; i += 256)
            w1b[i] = f2bf(W1[i]);
    } else if (do_x) {
        int n4 = nx >> 2;
        int idx = (blockIdx.x - 1) * 256 + threadIdx.x;
        int stride = (gridDim.x - 1) * 256;
        for (int i = idx; i < n4; i += stride) {
            float4 f = ((const float4*)x)[i];
            us4 o = { f2bf(f.x), f2bf(f.y), f2bf(f.z), f2bf(f.w) };
            ((us4*)xb)[i] = o;
        }
    }
}

#define MFMA4(AF, KS)                                                              \
    {                                                                              \
        const int kb_ = (KS) * 16 + kg * 8;                                        \
        acc[0] = __builtin_amdgcn_mfma_f32_32x32x16_bf16(                          \
            (AF), *(const bf16x8*)&W1s[0 * 32 + m][kb_], acc[0], 0, 0, 0);         \
        acc[1] = __builtin_amdgcn_mfma_f32_32x32x16_bf16(                          \
            (AF), *(const bf16x8*)&W1s[1 * 32 + m][kb_], acc[1], 0, 0, 0);         \
        acc[2] = __builtin_amdgcn_mfma_f32_32x32x16_bf16(                          \
            (AF), *(const bf16x8*)&W1s[2 * 32 + m][kb_], acc[2], 0, 0, 0);         \
        acc[3] = __builtin_amdgcn_mfma_f32_32x32x16_bf16(                          \
            (AF), *(const bf16x8*)&W1s[3 * 32 + m][kb_], acc[3], 0, 0, 0);         \
    }

// 2 tiles (256 edges) per block, sequential; all index/ef loads issued at
// kernel entry (overlap W1 staging + barrier); tile1 gathers issued after
// tile0's acc->s reduction (acc AGPRs dead, recycled). No extra barriers.
__global__ __launch_bounds__(256) void edge_mlp2(
    const unsigned short* __restrict__ xb,
    const int* __restrict__ ei, const float* __restrict__ ef,
    const unsigned short* __restrict__ w1b,
    const float* __restrict__ b1, const float* __restrict__ w2,
    const float* __restrict__ b2, float* __restrict__ out, int E, int ntiles)
{
    __shared__ unsigned short W1s[128][168];  // pad 160->168: 16B-aligned rows
    __shared__ float b1s[128];
    __shared__ float w2s[128];

    const int tid  = threadIdx.x;
    const int lane = tid & 63;
    const int wv   = tid >> 6;
    const int m    = lane & 31;   // A row / B col / C col
    const int kg   = lane >> 5;   // k half: k = ks*16 + kg*8 + j
    const int laneoff = wv * 32 + m;

    const int t0 = blockIdx.x * 2;
    const int t1 = t0 + 1;

    auto eidx_of = [&](int tt) -> int {
        if (tt >= ntiles) tt = ntiles - 1;
        long e = (long)tt * 128 + laneoff;
        return (int)(e < (long)E ? e : (long)(E - 1));
    };
    const int eA = eidx_of(t0);
    const int eB = eidx_of(t1);

    // ---- issue ALL index + ef loads up front (overlap staging) ----
    int oA = ei[eA], dA = ei[(size_t)E + eA];
    int oB = ei[eB], dB = ei[(size_t)E + eB];
    const float4* peA = (const float4*)(ef + (size_t)eA * 32 + kg * 8);
    const float4* peB = (const float4*)(ef + (size_t)eB * 32 + kg * 8);
    float4 efA0 = peA[0], efA1 = peA[1], efA2 = peA[4], efA3 = peA[5];
    float4 efB0 = peB[0], efB1 = peB[1], efB2 = peB[4], efB3 = peB[5];

    // ---- stage W1 (bf16, 40KB) ----
    {
        int j = tid >> 1, h = tid & 1;
        const unsigned short* src = w1b + j * 160 + h * 80;
        unsigned short* dst = &W1s[j][h * 80];
        #pragma unroll
        for (int i = 0; i < 10; i++)
            *(us8*)(dst + i * 8) = *(const us8*)(src + i * 8);
    }
    if (tid < 128) { b1s[tid] = b1[tid]; w2s[tid] = w2[tid]; }

    // ---- tile0 gathers (indices have ~staging-time to arrive) ----
    const unsigned short* xk = xb + kg * 8;
    bf16x8 xo[4], xd[4];
    {
        const bf16x8* po = (const bf16x8*)(xk + (size_t)oA * 64);
        const bf16x8* pd = (const bf16x8*)(xk + (size_t)dA * 64);
        #pragma unroll
        for (int ks = 0; ks < 4; ks++) { xo[ks] = po[ks * 2]; xd[ks] = pd[ks * 2]; }
    }
    bf16x8 af8 = pack8(efA0, efA1);
    bf16x8 af9 = pack8(efA2, efA3);

    __syncthreads();

    float b1v[4], w2v[4];
    #pragma unroll
    for (int nt = 0; nt < 4; nt++) {
        b1v[nt] = b1s[nt * 32 + m];
        w2v[nt] = w2s[nt * 32 + m];
    }
    const float b2v = b2[0];

    #pragma unroll
    for (int tt = 0; tt < 2; tt++) {
        const int tcur = (tt == 0) ? t0 : t1;

        f32x16 acc[4];
        #pragma unroll
        for (int i = 0; i < 4; i++)
            #pragma unroll
            for (int r = 0; r < 16; r++) acc[i][r] = 0.0f;

        #pragma unroll
        for (int ks = 0; ks < 4; ks++) MFMA4(xo[ks], ks);
        #pragma unroll
        for (int ks = 0; ks < 4; ks++) MFMA4(xd[ks], ks + 4);
        MFMA4(af8, 8);
        MFMA4(af9, 9);

        // ---- acc -> per-lane layer-2 partials (acc dead after this) ----
        float s[16];
        #pragma unroll
        for (int r = 0; r < 16; r++) {
            float a = 0.0f;
            #pragma unroll
            for (int nt = 0; nt < 4; nt++) {
                float h = acc[nt][r] + b1v[nt];
                h = fmaxf(h, 0.01f * h);
                a = fmaf(h, w2v[nt], a);
            }
            s[r] = a;
        }

        // ---- issue tile1 gathers under tile0's reduce/store ----
        if (tt == 0) {
            const bf16x8* po = (const bf16x8*)(xk + (size_t)oB * 64);
            const bf16x8* pd = (const bf16x8*)(xk + (size_t)dB * 64);
            #pragma unroll
            for (int ks = 0; ks < 4; ks++) { xo[ks] = po[ks * 2]; xd[ks] = pd[ks * 2]; }
            af8 = pack8(efB0, efB1);
            af9 = pack8(efB2, efB3);
        }

        // ---- butterfly: 16 regs over 32 cols in 16 shuffles ----
        #pragma unroll
        for (int k = 0; k < 4; k++) {
            const int msk = 1 << k;
            const int bit = (m >> k) & 1;
            #pragma unroll
            for (int j = 0; j < (8 >> k); j++) {
                float a0 = s[2 * j], a1 = s[2 * j + 1];
                float keep = bit ? a1 : a0;
                float send = bit ? a0 : a1;
                s[j] = keep + __shfl_xor(send, msk, 64);
            }
        }
        float tot = s[0] + __shfl_xor(s[0], 16, 64);

        if ((m & 16) == 0) {
            int row = (m & 3) + 4 * kg + 8 * ((m >> 2) & 3);
            long oidx = (long)tcur * 128 + wv * 32 + row;
            if (oidx < (long)E) {
                float v = tot + b2v;
                out[oidx] = fmaxf(v, 0.01f * v);
            }
        }
    }
}

// Fallback (ws too small for xb): proven non-persistent kernel, f32 gather.
__global__ __launch_bounds__(256) void edge_mlp_fb(
    const float* __restrict__ x,
    const int* __restrict__ ei, const float* __restrict__ ef,
    const unsigned short* __restrict__ w1b,
    const float* __restrict__ b1, const float* __restrict__ w2,
    const float* __restrict__ b2, float* __restrict__ out, int E)
{
    __shared__ unsigned short W1s[128][168];
    __shared__ float b1s[128];
    __shared__ float w2s[128];

    const int t = threadIdx.x;
    {
        int j = t >> 1, h = t & 1;
        const unsigned short* src = w1b + j * 160 + h * 80;
        unsigned short* dst = &W1s[j][h * 80];
        #pragma unroll
        for (int i = 0; i < 10; i++)
            *(us8*)(dst + i * 8) = *(const us8*)(src + i * 8);
    }
    if (t < 128) { b1s[t] = b1[t]; w2s[t] = w2[t]; }
    __syncthreads();

    const int lane = t & 63;
    const int wv   = t >> 6;
    const int m    = lane & 31;
    const int kg   = lane >> 5;
    const float b2v = b2[0];

    long e = (long)blockIdx.x * 128 + wv * 32 + m;
    int eidx = (int)((e < (long)E) ? e : (long)(E - 1));
    int o = ei[eidx];
    int d = ei[(size_t)E + eidx];

    bf16x8 afrag[10];
    {
        const float4* xo = (const float4*)(x + (size_t)o * 64 + kg * 8);
        const float4* xd = (const float4*)(x + (size_t)d * 64 + kg * 8);
        #pragma unroll
        for (int ks = 0; ks < 4; ks++) afrag[ks]     = pack8(xo[ks * 4], xo[ks * 4 + 1]);
        #pragma unroll
        for (int ks = 0; ks < 4; ks++) afrag[4 + ks] = pack8(xd[ks * 4], xd[ks * 4 + 1]);
        const float4* pef = (const float4*)(ef + (size_t)eidx * 32 + kg * 8);
        #pragma unroll
        for (int ks = 0; ks < 2; ks++)
            afrag[8 + ks] = pack8(pef[ks * 4], pef[ks * 4 + 1]);
    }

    f32x16 acc[4];
    #pragma unroll
    for (int i = 0; i < 4; i++)
        #pragma unroll
        for (int r = 0; r < 16; r++) acc[i][r] = 0.0f;

    #pragma unroll
    for (int ks = 0; ks < 10; ks++) {
        MFMA4(afrag[ks], ks);
    }

    float b1v[4], w2v[4];
    #pragma unroll
    for (int nt = 0; nt < 4; nt++) {
        b1v[nt] = b1s[nt * 32 + m];
        w2v[nt] = w2s[nt * 32 + m];
    }
    float s[16];
    #pragma unroll
    for (int r = 0; r < 16; r++) {
        float a = 0.0f;
        #pragma unroll
        for (int nt = 0; nt < 4; nt++) {
            float h = acc[nt][r] + b1v[nt];
            h = fmaxf(h, 0.01f * h);
            a = fmaf(h, w2v[nt], a);
        }
        s[r] = a;
    }
    #pragma unroll
    for (int k = 0; k < 4; k++) {
        const int msk = 1 << k;
        const int bit = (m >> k) & 1;
        #pragma unroll
        for (int j = 0; j < (8 >> k); j++) {
            float a0 = s[2 * j], a1 = s[2 * j + 1];
            float keep = bit ? a1 : a0;
            float send = bit ? a0 : a1;
            s[j] = keep + __shfl_xor(send, msk, 64);
        }
    }
    float tot = s[0] + __shfl_xor(s[0], 16, 64);

    if ((m & 16) == 0) {
        int row = (m & 3) + 4 * kg + 8 * ((m >> 2) & 3);
        long oidx = (long)blockIdx.x * 128 + wv * 32 + row;
        if (oidx < (long)E) {
            float v = tot + b2v;
            out[oidx] = fmaxf(v, 0.01f * v);
        }
    }
}

extern "C" void kernel_launch(void* const* d_in, const int* in_sizes, int n_in,
                              void* d_out, int out_size, void* d_ws, size_t ws_size,
                              hipStream_t stream)
{
    const float* x  = (const float*)d_in[0];
    const int*   ei = (const int*)d_in[1];
    const float* ef = (const float*)d_in[2];
    const float* W1 = (const float*)d_in[3];
    const float* b1 = (const float*)d_in[4];
    const float* w2 = (const float*)d_in[5];
    const float* b2 = (const float*)d_in[6];
    float* out = (float*)d_out;

    const int E  = in_sizes[1] / 2;
    const int nx = in_sizes[0];

    unsigned short* w1b = (unsigned short*)d_ws;
    unsigned short* xb  = (unsigned short*)((char*)d_ws + 65536);
    const bool use_xb = ws_size >= (size_t)65536 + (size_t)nx * 2;

    prep_kernel<<<use_xb ? 2048 : 1, 256, 0, stream>>>(W1, x, w1b, xb, nx, use_xb ? 1 : 0);
    if (use_xb) {
        const int ntiles = (E + 127) / 128;
        const int nblk = (ntiles + 1) / 2;
        edge_mlp2<<<nblk, 256, 0, stream>>>(xb, ei, ef, w1b, b1, w2, b2, out, E, ntiles);
    } else {
        const int nblk = (E + 127) / 128;
        edge_mlp_fb<<<nblk, 256, 0, stream>>>(x, ei, ef, w1b, b1, w2, b2, out, E);
    }
}

// Round 11
// 247.024 us; speedup vs baseline: 1.7300x; 1.0707x over previous
//
#include <hip/hip_runtime.h>
#include <hip/hip_bf16.h>

typedef __attribute__((ext_vector_type(8)))  short          bf16x8;
typedef __attribute__((ext_vector_type(8)))  unsigned short us8;
typedef __attribute__((ext_vector_type(4)))  unsigned short us4;
typedef __attribute__((ext_vector_type(16))) float          f32x16;

static __device__ __forceinline__ unsigned short f2bf(float f) {
    union { float f; unsigned int u; } v; v.f = f;
    unsigned int u = v.u;
    unsigned int r = u + 0x7fffu + ((u >> 16) & 1u);
    return (unsigned short)(r >> 16);
}

// 4x v_cvt_pk_bf16_f32 (RNE) replaces ~48 bit-trick VALU ops
static __device__ __forceinline__ bf16x8 pack8(float4 a, float4 b) {
    union { unsigned int u[4]; bf16x8 v; } r;
    asm("v_cvt_pk_bf16_f32 %0, %1, %2" : "=v"(r.u[0]) : "v"(a.x), "v"(a.y));
    asm("v_cvt_pk_bf16_f32 %0, %1, %2" : "=v"(r.u[1]) : "v"(a.z), "v"(a.w));
    asm("v_cvt_pk_bf16_f32 %0, %1, %2" : "=v"(r.u[2]) : "v"(b.x), "v"(b.y));
    asm("v_cvt_pk_bf16_f32 %0, %1, %2" : "=v"(r.u[3]) : "v"(b.z), "v"(b.w));
    return r.v;
}

// block 0: W1 f32 -> bf16 (5120 float4). blocks 1..: x f32 -> bf16 (if do_x)
__global__ __launch_bounds__(256) void prep_kernel(
    const float* __restrict__ W1, const float* __restrict__ x,
    unsigned short* __restrict__ w1b, unsigned short* __restrict__ xb,
    int nx, int do_x)
{
    if (blockIdx.x == 0) {
        for (int i = threadIdx.x; i < 5120; i += 256) {
            float4 f = ((const float4*)W1)[i];
            us4 o = { f2bf(f.x), f2bf(f.y), f2bf(f.z), f2bf(f.w) };
            ((us4*)w1b)[i] = o;
        }
    } else if (do_x) {
        int n4 = nx >> 2;
        int idx = (blockIdx.x - 1) * 256 + threadIdx.x;
        int stride = (gridDim.x - 1) * 256;
        for (int i = idx; i < n4; i += stride) {
            float4 f = ((const float4*)x)[i];
            us4 o = { f2bf(f.x), f2bf(f.y), f2bf(f.z), f2bf(f.w) };
            ((us4*)xb)[i] = o;
        }
    }
}

#define MFMA4(AF, KS)                                                              \
    {                                                                              \
        const int kb_ = (KS) * 16 + kg * 8;                                        \
        acc[0] = __builtin_amdgcn_mfma_f32_32x32x16_bf16(                          \
            (AF), *(const bf16x8*)&W1s[0 * 32 + m][kb_], acc[0], 0, 0, 0);         \
        acc[1] = __builtin_amdgcn_mfma_f32_32x32x16_bf16(                          \
            (AF), *(const bf16x8*)&W1s[1 * 32 + m][kb_], acc[1], 0, 0, 0);         \
        acc[2] = __builtin_amdgcn_mfma_f32_32x32x16_bf16(                          \
            (AF), *(const bf16x8*)&W1s[2 * 32 + m][kb_], acc[2], 0, 0, 0);         \
        acc[3] = __builtin_amdgcn_mfma_f32_32x32x16_bf16(                          \
            (AF), *(const bf16x8*)&W1s[3 * 32 + m][kb_], acc[3], 0, 0, 0);         \
    }

// Grid-strided long-lived blocks (768 = 3/CU residency limit); W1 staged once;
// rolling pipeline: gathers(t+1) issued after acc->s, ef 1 tile ahead,
// ei 2 tiles ahead. No per-tile barriers.
__global__ __launch_bounds__(256) void edge_mlp_p(
    const unsigned short* __restrict__ xb,
    const int* __restrict__ ei, const float* __restrict__ ef,
    const unsigned short* __restrict__ w1b,
    const float* __restrict__ b1, const float* __restrict__ w2,
    const float* __restrict__ b2, float* __restrict__ out, int E, int ntiles)
{
    __shared__ unsigned short W1s[128][168];  // pad 160->168: 16B-aligned rows

    const int tid  = threadIdx.x;
    const int lane = tid & 63;
    const int wv   = tid >> 6;
    const int m    = lane & 31;   // A row / B col / C col
    const int kg   = lane >> 5;   // k half: k = ks*16 + kg*8 + j
    const int laneoff = wv * 32 + m;
    const int NT = gridDim.x;
    const int Em1 = E - 1;
    const int estep = NT * 128;

    int t = blockIdx.x;
    if (t >= ntiles) return;

    // ---- prologue: current-tile indices/ef, next-tile indices ----
    int ecur = min(t * 128 + laneoff, Em1);
    int o0 = ei[ecur], d0 = ei[(size_t)E + ecur];
    {
        const float4* pe = (const float4*)(ef + (size_t)ecur * 32 + kg * 8);
        // reuse f0..f3 rolling ef registers
        float4 f0 = pe[0], f1 = pe[1], f2 = pe[4], f3 = pe[5];
        // loop-invariant weights (per-lane registers, no LDS)
        float b1v[4], w2v[4];
        #pragma unroll
        for (int nt = 0; nt < 4; nt++) { b1v[nt] = b1[nt * 32 + m]; w2v[nt] = w2[nt * 32 + m]; }
        const float b2v = b2[0];

        int elin1 = t * 128 + laneoff + estep;   // next tile linear id
        int enext = min(elin1, Em1);
        int o1 = ei[enext], d1 = ei[(size_t)E + enext];

        // ---- stage W1 once ----
        {
            int j = tid >> 1, h = tid & 1;
            const unsigned short* src = w1b + j * 160 + h * 80;
            unsigned short* dst = &W1s[j][h * 80];
            #pragma unroll
            for (int i = 0; i < 10; i++)
                *(us8*)(dst + i * 8) = *(const us8*)(src + i * 8);
        }

        // ---- tile-t gathers (ei latency covered by staging) ----
        const unsigned short* xk = xb + kg * 8;
        bf16x8 xo[4], xd[4];
        {
            const bf16x8* po = (const bf16x8*)(xk + (size_t)o0 * 64);
            const bf16x8* pd = (const bf16x8*)(xk + (size_t)d0 * 64);
            #pragma unroll
            for (int ks = 0; ks < 4; ks++) { xo[ks] = po[ks * 2]; xd[ks] = pd[ks * 2]; }
        }
        bf16x8 af8 = pack8(f0, f1);
        bf16x8 af9 = pack8(f2, f3);
        // issue ef for next tile (full-tile latency cover)
        {
            const float4* pe2 = (const float4*)(ef + (size_t)enext * 32 + kg * 8);
            f0 = pe2[0]; f1 = pe2[1]; f2 = pe2[4]; f3 = pe2[5];
        }

        __syncthreads();

        while (true) {
            f32x16 acc[4];
            #pragma unroll
            for (int i = 0; i < 4; i++)
                #pragma unroll
                for (int r = 0; r < 16; r++) acc[i][r] = 0.0f;

            __builtin_amdgcn_s_setprio(1);
            #pragma unroll
            for (int ks = 0; ks < 4; ks++) MFMA4(xo[ks], ks);
            #pragma unroll
            for (int ks = 0; ks < 4; ks++) MFMA4(xd[ks], ks + 4);
            MFMA4(af8, 8);
            MFMA4(af9, 9);
            __builtin_amdgcn_s_setprio(0);

            // ---- layer-2 partials (acc dead after) ----
            float s[16];
            #pragma unroll
            for (int r = 0; r < 16; r++) {
                float a = 0.0f;
                #pragma unroll
                for (int nt = 0; nt < 4; nt++) {
                    float h = acc[nt][r] + b1v[nt];
                    h = fmaxf(h, 0.01f * h);
                    a = fmaf(h, w2v[nt], a);
                }
                s[r] = a;
            }

            const int tn = t + NT;
            const bool more = (tn < ntiles);
            if (more) {
                // gathers for next tile (indices arrived one tile ago)
                const bf16x8* po = (const bf16x8*)(xk + (size_t)o1 * 64);
                const bf16x8* pd = (const bf16x8*)(xk + (size_t)d1 * 64);
                #pragma unroll
                for (int ks = 0; ks < 4; ks++) { xo[ks] = po[ks * 2]; xd[ks] = pd[ks * 2]; }
                // ei prefetch for t+2NT (2-tile cover)
                int e2 = min(elin1 + estep, Em1);
                o1 = ei[e2]; d1 = ei[(size_t)E + e2];
                // pack next-tile ef (arrived), then reissue ef for t+2NT
                af8 = pack8(f0, f1); af9 = pack8(f2, f3);
                const float4* pe2 = (const float4*)(ef + (size_t)e2 * 32 + kg * 8);
                f0 = pe2[0]; f1 = pe2[1]; f2 = pe2[4]; f3 = pe2[5];
            }

            // ---- butterfly: 16 regs over 32 cols in 16 shuffles ----
            #pragma unroll
            for (int k = 0; k < 4; k++) {
                const int msk = 1 << k;
                const int bit = (m >> k) & 1;
                #pragma unroll
                for (int j = 0; j < (8 >> k); j++) {
                    float a0 = s[2 * j], a1 = s[2 * j + 1];
                    float keep = bit ? a1 : a0;
                    float send = bit ? a0 : a1;
                    s[j] = keep + __shfl_xor(send, msk, 64);
                }
            }
            float tot = s[0] + __shfl_xor(s[0], 16, 64);

            if ((m & 16) == 0) {
                int row = (m & 3) + 4 * kg + 8 * ((m >> 2) & 3);
                long oidx = (long)t * 128 + wv * 32 + row;
                if (oidx < (long)E) {
                    float v = tot + b2v;
                    out[oidx] = fmaxf(v, 0.01f * v);
                }
            }

            if (!more) break;
            t = tn;
            elin1 += estep;
        }
    }
}

// Fallback (ws too small for xb): proven non-persistent kernel, f32 gather.
__global__ __launch_bounds__(256) void edge_mlp_fb(
    const float* __restrict__ x,
    const int* __restrict__ ei, const float* __restrict__ ef,
    const unsigned short* __restrict__ w1b,
    const float* __restrict__ b1, const float* __restrict__ w2,
    const float* __restrict__ b2, float* __restrict__ out, int E)
{
    __shared__ unsigned short W1s[128][168];
    __shared__ float b1s[128];
    __shared__ float w2s[128];

    const int t = threadIdx.x;
    {
        int j = t >> 1, h = t & 1;
        const unsigned short* src = w1b + j * 160 + h * 80;
        unsigned short* dst = &W1s[j][h * 80];
        #pragma unroll
        for (int i = 0; i < 10; i++)
            *(us8*)(dst + i * 8) = *(const us8*)(src + i * 8);
    }
    if (t < 128) { b1s[t] = b1[t]; w2s[t] = w2[t]; }
    __syncthreads();

    const int lane = t & 63;
    const int wv   = t >> 6;
    const int m    = lane & 31;
    const int kg   = lane >> 5;
    const float b2v = b2[0];

    long e = (long)blockIdx.x * 128 + wv * 32 + m;
    int eidx = (int)((e < (long)E) ? e : (long)(E - 1));
    int o = ei[eidx];
    int d = ei[(size_t)E + eidx];

    bf16x8 afrag[10];
    {
        const float4* xo = (const float4*)(x + (size_t)o * 64 + kg * 8);
        const float4* xd = (const float4*)(x + (size_t)d * 64 + kg * 8);
        #pragma unroll
        for (int ks = 0; ks < 4; ks++) afrag[ks]     = pack8(xo[ks * 4], xo[ks * 4 + 1]);
        #pragma unroll
        for (int ks = 0; ks < 4; ks++) afrag[4 + ks] = pack8(xd[ks * 4], xd[ks * 4 + 1]);
        const float4* pef = (const float4*)(ef + (size_t)eidx * 32 + kg * 8);
        #pragma unroll
        for (int ks = 0; ks < 2; ks++)
            afrag[8 + ks] = pack8(pef[ks * 4], pef[ks * 4 + 1]);
    }

    f32x16 acc[4];
    #pragma unroll
    for (int i = 0; i < 4; i++)
        #pragma unroll
        for (int r = 0; r < 16; r++) acc[i][r] = 0.0f;

    #pragma unroll
    for (int ks = 0; ks < 10; ks++) {
        MFMA4(afrag[ks], ks);
    }

    float b1v[4], w2v[4];
    #pragma unroll
    for (int nt = 0; nt < 4; nt++) {
        b1v[nt] = b1s[nt * 32 + m];
        w2v[nt] = w2s[nt * 32 + m];
    }
    float s[16];
    #pragma unroll
    for (int r = 0; r < 16; r++) {
        float a = 0.0f;
        #pragma unroll
        for (int nt = 0; nt < 4; nt++) {
            float h = acc[nt][r] + b1v[nt];
            h = fmaxf(h, 0.01f * h);
            a = fmaf(h, w2v[nt], a);
        }
        s[r] = a;
    }
    #pragma unroll
    for (int k = 0; k < 4; k++) {
        const int msk = 1 << k;
        const int bit = (m >> k) & 1;
        #pragma unroll
        for (int j = 0; j < (8 >> k); j++) {
            float a0 = s[2 * j], a1 = s[2 * j + 1];
            float keep = bit ? a1 : a0;
            float send = bit ? a0 : a1;
            s[j] = keep + __shfl_xor(send, msk, 64);
        }
    }
    float tot = s[0] + __shfl_xor(s[0], 16, 64);

    if ((m & 16) == 0) {
        int row = (m & 3) + 4 * kg + 8 * ((m >> 2) & 3);
        long oidx = (long)blockIdx.x * 128 + wv * 32 + row;
        if (oidx < (long)E) {
            float v = tot + b2v;
            out[oidx] = fmaxf(v, 0.01f * v);
        }
    }
}

extern "C" void kernel_launch(void* const* d_in, const int* in_sizes, int n_in,
                              void* d_out, int out_size, void* d_ws, size_t ws_size,
                              hipStream_t stream)
{
    const float* x  = (const float*)d_in[0];
    const int*   ei = (const int*)d_in[1];
    const float* ef = (const float*)d_in[2];
    const float* W1 = (const float*)d_in[3];
    const float* b1 = (const float*)d_in[4];
    const float* w2 = (const float*)d_in[5];
    const float* b2 = (const float*)d_in[6];
    float* out = (float*)d_out;

    const int E  = in_sizes[1] / 2;
    const int nx = in_sizes[0];

    unsigned short* w1b = (unsigned short*)d_ws;
    unsigned short* xb  = (unsigned short*)((char*)d_ws + 65536);
    const bool use_xb = ws_size >= (size_t)65536 + (size_t)nx * 2;

    prep_kernel<<<use_xb ? 2048 : 1, 256, 0, stream>>>(W1, x, w1b, xb, nx, use_xb ? 1 : 0);
    if (use_xb) {
        const int ntiles = (E + 127) / 128;
        const int nblk = ntiles < 768 ? ntiles : 768;
        edge_mlp_p<<<nblk, 256, 0, stream>>>(xb, ei, ef, w1b, b1, w2, b2, out, E, ntiles);
    } else {
        const int nblk = (E + 127) / 128;
        edge_mlp_fb<<<nblk, 256, 0, stream>>>(x, ei, ef, w1b, b1, w2, b2, out, E);
    }
}